// Round 9
// baseline (43.578 us; speedup 1.0000x reference)
//
#include <hip/hip_runtime.h>
#include <cstdint>
#include <cstddef>

#define HID 128
#define A_DIM 32

// ws layout (floats):
//   [0, 128)         Wa1 = W @ a_w[:128]
//   [128, 256)       Wa2 = W @ a_w[128:]
//   [256, 16640)     P[d][o] = sum_h W[d][h]*out_w[o][h]   (= W @ out_w^T)
// total ~66 KB. U lives in LDS inside fused_kernel.

// ---- k0: P (blocks 0..63) + Wa1/Wa2 (block 64) ----
__global__ __launch_bounds__(256) void prep_kernel(const float* __restrict__ W,
                                                   const float* __restrict__ a_w,
                                                   const float* __restrict__ out_w,
                                                   float* __restrict__ ws) {
    const int tid = threadIdx.x;
    const float4* W4 = reinterpret_cast<const float4*>(W);
    if (blockIdx.x < 64) {
        const int g = blockIdx.x * 256 + tid;
        const int d = g >> 7, o = g & 127;
        const float4* ow4 = reinterpret_cast<const float4*>(out_w);
        float p = 0.f;
#pragma unroll 8
        for (int j = 0; j < 32; ++j) {
            float4 wv = W4[d * 32 + j];   // broadcast within wave
            float4 ov = ow4[o * 32 + j];  // L2-resident
            p += wv.x * ov.x + wv.y * ov.y + wv.z * ov.z + wv.w * ov.w;
        }
        ws[256 + d * HID + o] = p;  // P[d][o], coalesced in o
    } else {
        const int row = tid & 127, which = tid >> 7;
        const float4* av = reinterpret_cast<const float4*>(a_w) + which * 32;
        float s = 0.f;
#pragma unroll 8
        for (int j = 0; j < 32; ++j) {
            float4 wv = W4[row * 32 + j];
            float4 va = av[j];
            s += wv.x * va.x + wv.y * va.y + wv.z * va.z + wv.w * va.w;
        }
        ws[tid] = s;
    }
}

#define E2_ROW(i, vv)                                                          \
    {                                                                          \
        float p2 = vv.x * w2.x + vv.y * w2.y + vv.z * w2.z + vv.w * w2.w;      \
        red[w][2 * (i) + half][q] = p2;                                        \
    }

#define WSUM_ROW(i, vv)                                                        \
    {                                                                          \
        float c = cf[w][2 * (i) + half];                                       \
        acc.x += c * vv.x;                                                     \
        acc.y += c * vv.y;                                                     \
        acc.z += c * vv.z;                                                     \
        acc.w += c * vv.w;                                                     \
    }

#define PIN4(a, b, c, d)                                                       \
    asm volatile("" : "+v"(a.x), "+v"(a.y), "+v"(a.z), "+v"(a.w),              \
                      "+v"(b.x), "+v"(b.y), "+v"(b.z), "+v"(b.w),              \
                      "+v"(c.x), "+v"(c.y), "+v"(c.z), "+v"(c.w),              \
                      "+v"(d.x), "+v"(d.y), "+v"(d.z), "+v"(d.w))

// ---- k1: fused attention (one wave per (b,i) pair, wave-synchronous) +
// in-block coalesced-P output projection using ALL 256 threads.
// __launch_bounds__(256,5): cap VGPR at 102 -> 5 waves/SIMD. ----
__global__ __launch_bounds__(256, 5) void fused_kernel(
    const float* __restrict__ hmat,
    const float* __restrict__ message,
    const int* __restrict__ mask,
    const float* __restrict__ ws,
    const float* __restrict__ out_b,
    float* __restrict__ out) {
    __shared__ float red[4][A_DIM][33];  // e2 partials; REUSED as epilogue partials
    __shared__ float cf[4][A_DIM];
    __shared__ float u_lds[4][HID];      // the block's 4 U rows

    const int tid = threadIdx.x;
    const int w = tid >> 6;
    const int lane = tid & 63;
    const int half = lane >> 5;
    const int q = lane & 31;
    const size_t bid = (size_t)blockIdx.x * 4 + w;  // flattened (b,i)

    // ---- batch-issue ALL global loads ----
    const float4* gm4 = reinterpret_cast<const float4*>(message) + bid * (A_DIM * HID / 4);
    float4 v0 = gm4[(0 + half) * 32 + q];
    float4 v1 = gm4[(2 + half) * 32 + q];
    float4 v2 = gm4[(4 + half) * 32 + q];
    float4 v3 = gm4[(6 + half) * 32 + q];
    float4 v4 = gm4[(8 + half) * 32 + q];
    float4 v5 = gm4[(10 + half) * 32 + q];
    float4 v6 = gm4[(12 + half) * 32 + q];
    float4 v7 = gm4[(14 + half) * 32 + q];
    float4 v8 = gm4[(16 + half) * 32 + q];
    float4 v9 = gm4[(18 + half) * 32 + q];
    float4 v10 = gm4[(20 + half) * 32 + q];
    float4 v11 = gm4[(22 + half) * 32 + q];
    float4 v12 = gm4[(24 + half) * 32 + q];
    float4 v13 = gm4[(26 + half) * 32 + q];
    float4 v14 = gm4[(28 + half) * 32 + q];
    float4 v15 = gm4[(30 + half) * 32 + q];
    const float4* ws4 = reinterpret_cast<const float4*>(ws);
    float4 w1 = ws4[q];       // Wa1
    float4 w2 = ws4[32 + q];  // Wa2
    float4 h4 = (reinterpret_cast<const float4*>(hmat) + bid * 32)[q];
    float mv = (float)mask[bid * A_DIM + q];

    PIN4(v0, v1, v2, v3);
    PIN4(v4, v5, v6, v7);
    PIN4(v8, v9, v10, v11);
    PIN4(v12, v13, v14, v15);

    // ---- e1 = dot(h, Wa1) ----
    float pe1 = (half == 0) ? (h4.x * w1.x + h4.y * w1.y + h4.z * w1.z + h4.w * w1.w) : 0.f;
#pragma unroll
    for (int m = 32; m >= 1; m >>= 1) pe1 += __shfl_xor(pe1, m);

    // ---- e2 partials -> padded LDS ----
    E2_ROW(0, v0) E2_ROW(1, v1) E2_ROW(2, v2) E2_ROW(3, v3)
    E2_ROW(4, v4) E2_ROW(5, v5) E2_ROW(6, v6) E2_ROW(7, v7)
    E2_ROW(8, v8) E2_ROW(9, v9) E2_ROW(10, v10) E2_ROW(11, v11)
    E2_ROW(12, v12) E2_ROW(13, v13) E2_ROW(14, v14) E2_ROW(15, v15)

    float e2 = 0.f;
#pragma unroll
    for (int k = 0; k < 16; ++k) e2 += red[w][q][16 * half + k];
    e2 += __shfl_xor(e2, 32);

    // ---- leaky-relu, mask, softmax (no max-subtract: |E| <~ 8, f32-safe) ----
    float e = pe1 + e2;
    e = (e >= 0.f) ? e : 0.2f * e;  // LeakyReLU(0.2)
    e *= mv;                        // E_mask (masked -> 0, not -inf)
    float ex = __expf(e);
    float sum = ex;
#pragma unroll
    for (int m = 16; m >= 1; m >>= 1) sum += __shfl_xor(sum, m);
    cf[w][q] = ex / sum * mv;  // alpha * m

    // ---- weighted message sum from registers ----
    float4 acc = {0.f, 0.f, 0.f, 0.f};
    WSUM_ROW(0, v0) WSUM_ROW(1, v1) WSUM_ROW(2, v2) WSUM_ROW(3, v3)
    WSUM_ROW(4, v4) WSUM_ROW(5, v5) WSUM_ROW(6, v6) WSUM_ROW(7, v7)
    WSUM_ROW(8, v8) WSUM_ROW(9, v9) WSUM_ROW(10, v10) WSUM_ROW(11, v11)
    WSUM_ROW(12, v12) WSUM_ROW(13, v13) WSUM_ROW(14, v14) WSUM_ROW(15, v15)
    acc.x += __shfl_xor(acc.x, 32);
    acc.y += __shfl_xor(acc.y, 32);
    acc.z += __shfl_xor(acc.z, 32);
    acc.w += __shfl_xor(acc.w, 32);

    if (half == 0) {
        float4 u;
        u.x = h4.x + acc.x;
        u.y = h4.y + acc.y;
        u.z = h4.z + acc.z;
        u.w = h4.w + acc.w;
        *reinterpret_cast<float4*>(&u_lds[w][4 * q]) = u;
    }
    __syncthreads();  // u_lds ready; red now dead for ALL waves

    // ---- epilogue: out[r][o] = elu(sum_d U[r][d]*P[d][o] + b[o]) ----
    // ALL 256 threads: tx = o-chunk (32), dq = d-group (8 groups of 16 d).
    const int tx = tid & 31;
    const int dq = tid >> 5;
    const float4* P4 = reinterpret_cast<const float4*>(ws + 256);
    float4 a0 = {0.f, 0.f, 0.f, 0.f}, a1 = a0, a2 = a0, a3 = a0;
#pragma unroll
    for (int j = 0; j < 16; ++j) {
        const int d = dq * 16 + j;
        float4 p = P4[d * 32 + tx];                // coalesced, L2/L1-resident
        float u0 = u_lds[0][d], u1 = u_lds[1][d];  // LDS broadcast
        float u2 = u_lds[2][d], u3 = u_lds[3][d];
        a0.x += u0 * p.x; a0.y += u0 * p.y; a0.z += u0 * p.z; a0.w += u0 * p.w;
        a1.x += u1 * p.x; a1.y += u1 * p.y; a1.z += u1 * p.z; a1.w += u1 * p.w;
        a2.x += u2 * p.x; a2.y += u2 * p.y; a2.z += u2 * p.z; a2.w += u2 * p.w;
        a3.x += u3 * p.x; a3.y += u3 * p.y; a3.z += u3 * p.z; a3.w += u3 * p.w;
    }
    // red is dead (all reads happened before the barrier above) — write partials now.
    float4* part4 = reinterpret_cast<float4*>(&red[0][0][0]);
    part4[(dq * 4 + 0) * 32 + tx] = a0;
    part4[(dq * 4 + 1) * 32 + tx] = a1;
    part4[(dq * 4 + 2) * 32 + tx] = a2;
    part4[(dq * 4 + 3) * 32 + tx] = a3;
    __syncthreads();

    // Combine 8 d-groups + bias + elu: 128 threads = 4 rows x 32 o-chunks.
    if (tid < 128) {
        const int r = tid >> 5;
        float4 s = part4[r * 32 + tx];
#pragma unroll
        for (int g = 1; g < 8; ++g) {
            float4 t = part4[(g * 4 + r) * 32 + tx];
            s.x += t.x; s.y += t.y; s.z += t.z; s.w += t.w;
        }
        float4 b4 = reinterpret_cast<const float4*>(out_b)[tx];
        float4 o4;
        float x;
        x = s.x + b4.x; o4.x = (x > 0.f) ? x : (__expf(x) - 1.0f);
        x = s.y + b4.y; o4.y = (x > 0.f) ? x : (__expf(x) - 1.0f);
        x = s.z + b4.z; o4.z = (x > 0.f) ? x : (__expf(x) - 1.0f);
        x = s.w + b4.w; o4.w = (x > 0.f) ? x : (__expf(x) - 1.0f);
        reinterpret_cast<float4*>(out)[((size_t)blockIdx.x * 4 + r) * 32 + tx] = o4;
    }
}

extern "C" void kernel_launch(void* const* d_in, const int* in_sizes, int n_in,
                              void* d_out, int out_size, void* d_ws, size_t ws_size,
                              hipStream_t stream) {
    const float* hmat = (const float*)d_in[0];     // (256,32,128)
    const float* message = (const float*)d_in[1];  // (256,32,32,128)
    const int* mask = (const int*)d_in[2];         // (256,32,32)
    const float* W = (const float*)d_in[3];        // (128,128)
    const float* a_w = (const float*)d_in[4];      // (256,)
    const float* out_w = (const float*)d_in[5];    // (128,128)
    const float* out_b = (const float*)d_in[6];    // (128,)
    float* out = (float*)d_out;                    // (256,32,128) f32
    float* ws = (float*)d_ws;

    prep_kernel<<<65, 256, 0, stream>>>(W, a_w, out_w, ws);
    fused_kernel<<<2048, 256, 0, stream>>>(hmat, message, mask, ws, out_b, out);
}

// Round 10
// 36.010 us; speedup vs baseline: 1.2102x; 1.2102x over previous
//
#include <hip/hip_runtime.h>
#include <cstdint>
#include <cstddef>

#define HID 128
#define A_DIM 32

// ws layout (floats):
//   [0, 128)         Wa1 = W @ a_w[:128]
//   [128, 256)       Wa2 = W @ a_w[128:]
//   [256, 16640)     P[d][o] = sum_h W[d][h]*out_w[o][h]   (= W @ out_w^T)
// total ~66 KB. U lives in LDS inside fused_kernel.

// ---- k0: P (blocks 0..63) + Wa1/Wa2 (block 64) ----
__global__ __launch_bounds__(256) void prep_kernel(const float* __restrict__ W,
                                                   const float* __restrict__ a_w,
                                                   const float* __restrict__ out_w,
                                                   float* __restrict__ ws) {
    const int tid = threadIdx.x;
    const float4* W4 = reinterpret_cast<const float4*>(W);
    if (blockIdx.x < 64) {
        const int g = blockIdx.x * 256 + tid;
        const int d = g >> 7, o = g & 127;
        const float4* ow4 = reinterpret_cast<const float4*>(out_w);
        float p = 0.f;
#pragma unroll 8
        for (int j = 0; j < 32; ++j) {
            float4 wv = W4[d * 32 + j];   // broadcast within wave
            float4 ov = ow4[o * 32 + j];  // L2-resident
            p += wv.x * ov.x + wv.y * ov.y + wv.z * ov.z + wv.w * ov.w;
        }
        ws[256 + d * HID + o] = p;  // P[d][o], coalesced in o
    } else {
        const int row = tid & 127, which = tid >> 7;
        const float4* av = reinterpret_cast<const float4*>(a_w) + which * 32;
        float s = 0.f;
#pragma unroll 8
        for (int j = 0; j < 32; ++j) {
            float4 wv = W4[row * 32 + j];
            float4 va = av[j];
            s += wv.x * va.x + wv.y * va.y + wv.z * va.z + wv.w * va.w;
        }
        ws[tid] = s;
    }
}

#define E2_ROW(i, vv)                                                          \
    {                                                                          \
        float p2 = vv.x * w2.x + vv.y * w2.y + vv.z * w2.z + vv.w * w2.w;      \
        red[w][2 * (i) + half][q] = p2;                                        \
    }

#define WSUM_ROW(i, vv)                                                        \
    {                                                                          \
        float c = cf[w][2 * (i) + half];                                       \
        acc.x += c * vv.x;                                                     \
        acc.y += c * vv.y;                                                     \
        acc.z += c * vv.z;                                                     \
        acc.w += c * vv.w;                                                     \
    }

#define PIN4(a, b, c, d)                                                       \
    asm volatile("" : "+v"(a.x), "+v"(a.y), "+v"(a.z), "+v"(a.w),              \
                      "+v"(b.x), "+v"(b.y), "+v"(b.z), "+v"(b.w),              \
                      "+v"(c.x), "+v"(c.y), "+v"(c.z), "+v"(c.w),              \
                      "+v"(d.x), "+v"(d.y), "+v"(d.z), "+v"(d.w))

// ---- k1: fused attention (one wave per (b,i) pair, wave-synchronous) +
// in-block coalesced-P output projection using ALL 256 threads.
// __launch_bounds__(256,4): the 64-VGPR pinned tile needs ~128 VGPRs;
// capping at 5 waves/SIMD (102 VGPR) spills and regresses (r9: +7.5us).
__global__ __launch_bounds__(256, 4) void fused_kernel(
    const float* __restrict__ hmat,
    const float* __restrict__ message,
    const int* __restrict__ mask,
    const float* __restrict__ ws,
    const float* __restrict__ out_b,
    float* __restrict__ out) {
    __shared__ float red[4][A_DIM][33];  // e2 partials; REUSED as epilogue partials
    __shared__ float cf[4][A_DIM];
    __shared__ float u_lds[4][HID];      // the block's 4 U rows

    const int tid = threadIdx.x;
    const int w = tid >> 6;
    const int lane = tid & 63;
    const int half = lane >> 5;
    const int q = lane & 31;
    const size_t bid = (size_t)blockIdx.x * 4 + w;  // flattened (b,i)

    // ---- batch-issue ALL global loads ----
    const float4* gm4 = reinterpret_cast<const float4*>(message) + bid * (A_DIM * HID / 4);
    float4 v0 = gm4[(0 + half) * 32 + q];
    float4 v1 = gm4[(2 + half) * 32 + q];
    float4 v2 = gm4[(4 + half) * 32 + q];
    float4 v3 = gm4[(6 + half) * 32 + q];
    float4 v4 = gm4[(8 + half) * 32 + q];
    float4 v5 = gm4[(10 + half) * 32 + q];
    float4 v6 = gm4[(12 + half) * 32 + q];
    float4 v7 = gm4[(14 + half) * 32 + q];
    float4 v8 = gm4[(16 + half) * 32 + q];
    float4 v9 = gm4[(18 + half) * 32 + q];
    float4 v10 = gm4[(20 + half) * 32 + q];
    float4 v11 = gm4[(22 + half) * 32 + q];
    float4 v12 = gm4[(24 + half) * 32 + q];
    float4 v13 = gm4[(26 + half) * 32 + q];
    float4 v14 = gm4[(28 + half) * 32 + q];
    float4 v15 = gm4[(30 + half) * 32 + q];
    const float4* ws4 = reinterpret_cast<const float4*>(ws);
    float4 w1 = ws4[q];       // Wa1
    float4 w2 = ws4[32 + q];  // Wa2
    float4 h4 = (reinterpret_cast<const float4*>(hmat) + bid * 32)[q];
    float mv = (float)mask[bid * A_DIM + q];

    PIN4(v0, v1, v2, v3);
    PIN4(v4, v5, v6, v7);
    PIN4(v8, v9, v10, v11);
    PIN4(v12, v13, v14, v15);

    // ---- e1 = dot(h, Wa1) ----
    float pe1 = (half == 0) ? (h4.x * w1.x + h4.y * w1.y + h4.z * w1.z + h4.w * w1.w) : 0.f;
#pragma unroll
    for (int m = 32; m >= 1; m >>= 1) pe1 += __shfl_xor(pe1, m);

    // ---- e2 partials -> padded LDS ----
    E2_ROW(0, v0) E2_ROW(1, v1) E2_ROW(2, v2) E2_ROW(3, v3)
    E2_ROW(4, v4) E2_ROW(5, v5) E2_ROW(6, v6) E2_ROW(7, v7)
    E2_ROW(8, v8) E2_ROW(9, v9) E2_ROW(10, v10) E2_ROW(11, v11)
    E2_ROW(12, v12) E2_ROW(13, v13) E2_ROW(14, v14) E2_ROW(15, v15)

    float e2 = 0.f;
#pragma unroll
    for (int k = 0; k < 16; ++k) e2 += red[w][q][16 * half + k];
    e2 += __shfl_xor(e2, 32);

    // ---- leaky-relu, mask, softmax (no max-subtract: |E| <~ 8, f32-safe) ----
    float e = pe1 + e2;
    e = (e >= 0.f) ? e : 0.2f * e;  // LeakyReLU(0.2)
    e *= mv;                        // E_mask (masked -> 0, not -inf)
    float ex = __expf(e);
    float sum = ex;
#pragma unroll
    for (int m = 16; m >= 1; m >>= 1) sum += __shfl_xor(sum, m);
    cf[w][q] = ex / sum * mv;  // alpha * m

    // ---- weighted message sum from registers ----
    float4 acc = {0.f, 0.f, 0.f, 0.f};
    WSUM_ROW(0, v0) WSUM_ROW(1, v1) WSUM_ROW(2, v2) WSUM_ROW(3, v3)
    WSUM_ROW(4, v4) WSUM_ROW(5, v5) WSUM_ROW(6, v6) WSUM_ROW(7, v7)
    WSUM_ROW(8, v8) WSUM_ROW(9, v9) WSUM_ROW(10, v10) WSUM_ROW(11, v11)
    WSUM_ROW(12, v12) WSUM_ROW(13, v13) WSUM_ROW(14, v14) WSUM_ROW(15, v15)
    acc.x += __shfl_xor(acc.x, 32);
    acc.y += __shfl_xor(acc.y, 32);
    acc.z += __shfl_xor(acc.z, 32);
    acc.w += __shfl_xor(acc.w, 32);

    if (half == 0) {
        float4 u;
        u.x = h4.x + acc.x;
        u.y = h4.y + acc.y;
        u.z = h4.z + acc.z;
        u.w = h4.w + acc.w;
        *reinterpret_cast<float4*>(&u_lds[w][4 * q]) = u;
    }
    __syncthreads();  // u_lds ready; red now dead for ALL waves

    // ---- epilogue: out[r][o] = elu(sum_d U[r][d]*P[d][o] + b[o]) ----
    // ALL 256 threads: tx = o-chunk (32), dq = d-group (8 groups of 16 d).
    const int tx = tid & 31;
    const int dq = tid >> 5;
    const float4* P4 = reinterpret_cast<const float4*>(ws + 256);
    float4 a0 = {0.f, 0.f, 0.f, 0.f}, a1 = a0, a2 = a0, a3 = a0;
#pragma unroll
    for (int j = 0; j < 16; ++j) {
        const int d = dq * 16 + j;
        float4 p = P4[d * 32 + tx];                // coalesced, L2/L1-resident
        float u0 = u_lds[0][d], u1 = u_lds[1][d];  // LDS broadcast
        float u2 = u_lds[2][d], u3 = u_lds[3][d];
        a0.x += u0 * p.x; a0.y += u0 * p.y; a0.z += u0 * p.z; a0.w += u0 * p.w;
        a1.x += u1 * p.x; a1.y += u1 * p.y; a1.z += u1 * p.z; a1.w += u1 * p.w;
        a2.x += u2 * p.x; a2.y += u2 * p.y; a2.z += u2 * p.z; a2.w += u2 * p.w;
        a3.x += u3 * p.x; a3.y += u3 * p.y; a3.z += u3 * p.z; a3.w += u3 * p.w;
    }
    // red is dead (all reads happened before the barrier above) — write partials now.
    float4* part4 = reinterpret_cast<float4*>(&red[0][0][0]);
    part4[(dq * 4 + 0) * 32 + tx] = a0;
    part4[(dq * 4 + 1) * 32 + tx] = a1;
    part4[(dq * 4 + 2) * 32 + tx] = a2;
    part4[(dq * 4 + 3) * 32 + tx] = a3;
    __syncthreads();

    // Combine 8 d-groups + bias + elu: 128 threads = 4 rows x 32 o-chunks.
    if (tid < 128) {
        const int r = tid >> 5;
        float4 s = part4[r * 32 + tx];
#pragma unroll
        for (int g = 1; g < 8; ++g) {
            float4 t = part4[(g * 4 + r) * 32 + tx];
            s.x += t.x; s.y += t.y; s.z += t.z; s.w += t.w;
        }
        float4 b4 = reinterpret_cast<const float4*>(out_b)[tx];
        float4 o4;
        float x;
        x = s.x + b4.x; o4.x = (x > 0.f) ? x : (__expf(x) - 1.0f);
        x = s.y + b4.y; o4.y = (x > 0.f) ? x : (__expf(x) - 1.0f);
        x = s.z + b4.z; o4.z = (x > 0.f) ? x : (__expf(x) - 1.0f);
        x = s.w + b4.w; o4.w = (x > 0.f) ? x : (__expf(x) - 1.0f);
        reinterpret_cast<float4*>(out)[((size_t)blockIdx.x * 4 + r) * 32 + tx] = o4;
    }
}

extern "C" void kernel_launch(void* const* d_in, const int* in_sizes, int n_in,
                              void* d_out, int out_size, void* d_ws, size_t ws_size,
                              hipStream_t stream) {
    const float* hmat = (const float*)d_in[0];     // (256,32,128)
    const float* message = (const float*)d_in[1];  // (256,32,32,128)
    const int* mask = (const int*)d_in[2];         // (256,32,32)
    const float* W = (const float*)d_in[3];        // (128,128)
    const float* a_w = (const float*)d_in[4];      // (256,)
    const float* out_w = (const float*)d_in[5];    // (128,128)
    const float* out_b = (const float*)d_in[6];    // (128,)
    float* out = (float*)d_out;                    // (256,32,128) f32
    float* ws = (float*)d_ws;

    prep_kernel<<<65, 256, 0, stream>>>(W, a_w, out_w, ws);
    fused_kernel<<<2048, 256, 0, stream>>>(hmat, message, mask, ws, out_b, out);
}